// Round 2
// baseline (451.494 us; speedup 1.0000x reference)
//
#include <hip/hip_runtime.h>
#include <hip/hip_fp16.h>

typedef _Float16 h8v __attribute__((ext_vector_type(8)));  // arithmetic type
typedef __fp16   hf8 __attribute__((ext_vector_type(8)));  // builtin ABI type
typedef float    f4v __attribute__((ext_vector_type(4)));
typedef unsigned int u32;

#define DEV __device__ __forceinline__

constexpr int NB    = 256;   // batch
constexpr int NHD   = 32;    // heads (S*Q)
constexpr int GG    = 4096;  // global_info_dim
constexpr int KHALF = 2048;  // per k-split half
constexpr int D1    = 512;   // 2H
constexpr int HD    = 256;   // H

// fp16 tile in LDS: 64 rows x 64 cols, stored as 32 dwords/row with an XOR
// swizzle so ds_read_b128 fragment reads are bank-uniform.
// phys dword index for (row, dword-col c in [0,32)):
DEV int swz(int row, int c) {
    return row*32 + ((((c>>2) ^ (row & 7)) & 7) << 2) + (c & 3);
}
DEV u32 pk2(float a, float b) {
    auto r = __builtin_amdgcn_cvt_pkrtz(a, b);   // __fp16 x2
    return __builtin_bit_cast(u32, r);
}
DEV f4v mfma16(h8v a, hf8 b, f4v c) {
    return __builtin_amdgcn_mfma_f32_16x16x32_f16(
        __builtin_bit_cast(hf8, a), b, c, 0, 0, 0);
}

// ------------- kernel 1: layernorm stats + fp16 pre-casts -------------------
__global__ __launch_bounds__(256) void k_prep(
        const float* __restrict__ ns, const float* __restrict__ pools,
        const float* __restrict__ lnw, const float* __restrict__ lnb,
        _Float16* __restrict__ xnh, _Float16* __restrict__ lnwh,
        _Float16* __restrict__ lnbh)
{
    const int t = threadIdx.x;
    const int bid = blockIdx.x;
    if (bid < NB) {
        // one block per batch row: gi = concat(ns[b], pools[b]), 4096 floats
        f4v v[4];
        float s = 0.f, s2 = 0.f;
        #pragma unroll
        for (int p = 0; p < 4; ++p) {
            int i4 = t + 256*p;                       // float4 index in [0,1024)
            const float* src = (i4 < 512) ? (ns + (size_t)bid*2048 + i4*4)
                                          : (pools + (size_t)bid*2048 + (i4-512)*4);
            v[p] = *(const f4v*)src;
            #pragma unroll
            for (int j = 0; j < 4; ++j) { s += v[p][j]; s2 += v[p][j]*v[p][j]; }
        }
        #pragma unroll
        for (int o = 32; o > 0; o >>= 1) { s += __shfl_down(s, o); s2 += __shfl_down(s2, o); }
        __shared__ float red[8];
        if ((t & 63) == 0) { red[t>>6] = s; red[4 + (t>>6)] = s2; }
        __syncthreads();
        float ts   = red[0]+red[1]+red[2]+red[3];
        float ts2  = red[4]+red[5]+red[6]+red[7];
        float mu   = ts  * (1.f/4096.f);
        float var  = ts2 * (1.f/4096.f) - mu*mu;
        float rstd = rsqrtf(var + 1e-5f);
        #pragma unroll
        for (int p = 0; p < 4; ++p) {
            int i4 = t + 256*p;
            u32 w0 = pk2((v[p][0]-mu)*rstd, (v[p][1]-mu)*rstd);
            u32 w1 = pk2((v[p][2]-mu)*rstd, (v[p][3]-mu)*rstd);
            *(uint2*)(xnh + (size_t)bid*GG + i4*4) = make_uint2(w0, w1);
        }
    } else {
        // 64 blocks convert ln_w / ln_b (32*4096 each) to fp16
        const int base = (bid - NB)*2048 + t*8;
        f4v a0 = *(const f4v*)(lnw + base);
        f4v a1 = *(const f4v*)(lnw + base + 4);
        *(uint2*)(lnwh + base)     = make_uint2(pk2(a0[0],a0[1]), pk2(a0[2],a0[3]));
        *(uint2*)(lnwh + base + 4) = make_uint2(pk2(a1[0],a1[1]), pk2(a1[2],a1[3]));
        f4v c0 = *(const f4v*)(lnb + base);
        f4v c1 = *(const f4v*)(lnb + base + 4);
        *(uint2*)(lnbh + base)     = make_uint2(pk2(c0[0],c0[1]), pk2(c0[2],c0[3]));
        *(uint2*)(lnbh + base + 4) = make_uint2(pk2(c1[0],c1[1]), pk2(c1[2],c1[3]));
    }
}

// ------------- kernel 2: h_part[ks] = (xn*lnw + lnb) @ W1  ------------------
// grid (8 d-tiles, 32 heads, 2 k-halves); block 256 = 4 waves.
// BM=256 (all batch rows -> W1 streamed exactly once), BN=64, BK=64.
// A-operand comes straight from global (xn_h is small & L2-hot); only the
// W1 tile is staged (fp32->fp16 transpose into swizzled LDS).
__global__ __launch_bounds__(256, 2) void k_gemm1(
        const _Float16* __restrict__ xnh, const _Float16* __restrict__ lnwh,
        const _Float16* __restrict__ lnbh, const float* __restrict__ W1,
        float* __restrict__ hp)
{
    const int dt = blockIdx.x;
    const int n  = blockIdx.y;
    const int ks = blockIdx.z;
    const int t  = threadIdx.x;
    const int l  = t & 63;
    const int w  = t >> 6;

    __shared__ u32 lb[64*32];

    const float*    W1p = W1  + ((size_t)n*GG + (size_t)ks*KHALF)*D1 + dt*64;
    const _Float16* xb  = xnh + ks*KHALF;
    const _Float16* lwp = lnwh + (size_t)n*GG + ks*KHALF;
    const _Float16* lbp = lnbh + (size_t)n*GG + ks*KHALF;

    // staging geometry: thread covers cols d0..d0+3 (output dim) x rows g0..g0+3 (k)
    const int d0 = 4*(t & 15);
    const int g0 = 4*(t >> 4);
    int wp[4];
    #pragma unroll
    for (int i = 0; i < 4; ++i) wp[i] = swz(d0 + i, g0 >> 1);

    // per-wave fragment read offsets (invariant across K loop)
    int rp[2][4];
    #pragma unroll
    for (int kc = 0; kc < 2; ++kc)
        #pragma unroll
        for (int ni = 0; ni < 4; ++ni) {
            int nr = ni*16 + (l & 15);
            int qq = kc*4 + (l >> 4);
            rp[kc][ni] = nr*32 + (((qq ^ (nr & 7)) & 7) << 2);
        }

    f4v st[4];
    #pragma unroll
    for (int p = 0; p < 4; ++p)
        st[p] = *(const f4v*)(W1p + (size_t)(g0 + p)*D1 + d0);

    f4v acc[4][4];
    #pragma unroll
    for (int mi = 0; mi < 4; ++mi)
        #pragma unroll
        for (int ni = 0; ni < 4; ++ni)
            #pragma unroll
            for (int r = 0; r < 4; ++r) acc[mi][ni][r] = 0.f;

    const int r0 = w*64;   // wave's 64 batch rows

    for (int kt = 0; kt < KHALF/64; ++kt) {
        __syncthreads();
        // transpose-write staged W1 tile (fp16 pairs along k) into swizzled LDS
        #pragma unroll
        for (int i = 0; i < 4; ++i) {
            u32 lo = pk2(st[0][i], st[1][i]);   // k = g0, g0+1
            u32 hi = pk2(st[2][i], st[3][i]);   // k = g0+2, g0+3
            *(uint2*)&lb[wp[i]] = make_uint2(lo, hi);
        }
        __syncthreads();
        // prefetch next W1 tile into regs (overlaps with compute below)
        if (kt + 1 < KHALF/64) {
            const float* src = W1p + (size_t)(kt + 1)*64*D1;
            #pragma unroll
            for (int p = 0; p < 4; ++p)
                st[p] = *(const f4v*)(src + (size_t)(g0 + p)*D1 + d0);
        }
        #pragma unroll
        for (int kc = 0; kc < 2; ++kc) {
            const int ko = kt*64 + kc*32 + 8*(l >> 4);
            h8v lw8 = *(const h8v*)(lwp + ko);
            h8v lb8 = *(const h8v*)(lbp + ko);
            h8v a[4];
            #pragma unroll
            for (int mi = 0; mi < 4; ++mi) {
                const _Float16* ap = xb + (size_t)(r0 + mi*16 + (l & 15))*GG + ko;
                h8v x = *(const h8v*)ap;
                a[mi] = x*lw8 + lb8;            // per-head LN affine, v_pk_fma_f16
            }
            #pragma unroll
            for (int ni = 0; ni < 4; ++ni) {
                hf8 bf = __builtin_bit_cast(hf8, *(const uint4*)&lb[rp[kc][ni]]);
                #pragma unroll
                for (int mi = 0; mi < 4; ++mi)
                    acc[mi][ni] = mfma16(a[mi], bf, acc[mi][ni]);
            }
        }
    }

    float* outp = hp + (size_t)ks*NB*NHD*D1;
    #pragma unroll
    for (int mi = 0; mi < 4; ++mi)
        #pragma unroll
        for (int ni = 0; ni < 4; ++ni)
            #pragma unroll
            for (int r = 0; r < 4; ++r) {
                int brow = r0 + mi*16 + (l >> 4)*4 + r;   // C layout: col=l&15, row=(l>>4)*4+r
                int dd   = dt*64 + ni*16 + (l & 15);
                outp[((size_t)brow*NHD + n)*D1 + dd] = acc[mi][ni][r];
            }
}

// ------------- kernel 3: out = silu(hp0+hp1+b1) @ W2 + b2 + qe + pools ------
// grid (4 h-tiles, 4 b-tiles, 32 heads); block 256 = 4 waves (2x2, 32x32 each)
__global__ __launch_bounds__(256, 2) void k_gemm2(
        const float* __restrict__ hp, const float* __restrict__ b1,
        const float* __restrict__ W2, const float* __restrict__ b2,
        const float* __restrict__ qe, const float* __restrict__ pools,
        float* __restrict__ out)
{
    const int ht = blockIdx.x;
    const int bt = blockIdx.y;
    const int n  = blockIdx.z;
    const int t  = threadIdx.x;
    const int l  = t & 63;
    const int w  = t >> 6;
    const int wr = w >> 1, wc = w & 1;

    __shared__ u32 la[64*32];
    __shared__ u32 lbs[64*32];

    const size_t HPH = (size_t)NB*NHD*D1;
    const float* W2p = W2 + (size_t)n*D1*HD + ht*64;

    const int d0 = 4*(t & 15);    // B: hh quad
    const int g0 = 4*(t >> 4);    // B: k (dd) quad
    const int ar = t >> 4;        // A: row base (+16p)
    const int ak = 4*(t & 15);    // A: k (dd) quad

    int wpB[4], wpA[4];
    #pragma unroll
    for (int i = 0; i < 4; ++i) wpB[i] = swz(d0 + i, g0 >> 1);
    #pragma unroll
    for (int p = 0; p < 4; ++p) wpA[p] = swz(ar + 16*p, ak >> 1);

    f4v acc[2][2];
    #pragma unroll
    for (int mi = 0; mi < 2; ++mi)
        #pragma unroll
        for (int ni = 0; ni < 2; ++ni)
            #pragma unroll
            for (int r = 0; r < 4; ++r) acc[mi][ni][r] = 0.f;

    for (int kt = 0; kt < D1/64; ++kt) {
        __syncthreads();
        // A tile: silu(hp0+hp1+b1) -> fp16, k-contiguous rows
        #pragma unroll
        for (int p = 0; p < 4; ++p) {
            int r = ar + 16*p;
            size_t ro = ((size_t)(bt*64 + r)*NHD + n)*D1 + kt*64 + ak;
            f4v x0 = *(const f4v*)(hp + ro);
            f4v x1 = *(const f4v*)(hp + HPH + ro);
            f4v bb = *(const f4v*)(b1 + n*D1 + kt*64 + ak);
            float y[4];
            #pragma unroll
            for (int j = 0; j < 4; ++j) {
                float xv = x0[j] + x1[j] + bb[j];
                y[j] = xv / (1.f + __expf(-xv));
            }
            *(uint2*)&la[wpA[p]] = make_uint2(pk2(y[0], y[1]), pk2(y[2], y[3]));
        }
        // B tile: W2 transpose-staged like gemm1
        f4v sw[4];
        #pragma unroll
        for (int p = 0; p < 4; ++p)
            sw[p] = *(const f4v*)(W2p + (size_t)(kt*64 + g0 + p)*HD + d0);
        #pragma unroll
        for (int i = 0; i < 4; ++i)
            *(uint2*)&lbs[wpB[i]] = make_uint2(pk2(sw[0][i], sw[1][i]), pk2(sw[2][i], sw[3][i]));
        __syncthreads();
        #pragma unroll
        for (int kc = 0; kc < 2; ++kc) {
            h8v a[2]; hf8 bf[2];
            #pragma unroll
            for (int mi = 0; mi < 2; ++mi) {
                int row = wr*32 + mi*16 + (l & 15);
                int qq  = kc*4 + (l >> 4);
                a[mi] = __builtin_bit_cast(h8v, *(const uint4*)&la[row*32 + (((qq ^ (row & 7)) & 7) << 2)]);
            }
            #pragma unroll
            for (int ni = 0; ni < 2; ++ni) {
                int col = wc*32 + ni*16 + (l & 15);
                int qq  = kc*4 + (l >> 4);
                bf[ni] = __builtin_bit_cast(hf8, *(const uint4*)&lbs[col*32 + (((qq ^ (col & 7)) & 7) << 2)]);
            }
            #pragma unroll
            for (int mi = 0; mi < 2; ++mi)
                #pragma unroll
                for (int ni = 0; ni < 2; ++ni)
                    acc[mi][ni] = mfma16(a[mi], bf[ni], acc[mi][ni]);
        }
    }

    const int s = n >> 2;
    #pragma unroll
    for (int mi = 0; mi < 2; ++mi)
        #pragma unroll
        for (int ni = 0; ni < 2; ++ni) {
            int hh = ht*64 + wc*32 + ni*16 + (l & 15);
            float add0 = b2[n*HD + hh] + qe[n*HD + hh];
            #pragma unroll
            for (int r = 0; r < 4; ++r) {
                int brow = bt*64 + wr*32 + mi*16 + (l >> 4)*4 + r;
                float v = acc[mi][ni][r] + add0 + pools[(size_t)brow*2048 + s*256 + hh];
                out[(size_t)brow*(NHD*HD) + n*HD + hh] = v;
            }
        }
}

extern "C" void kernel_launch(void* const* d_in, const int* in_sizes, int n_in,
                              void* d_out, int out_size, void* d_ws, size_t ws_size,
                              hipStream_t stream) {
    const float* ns   = (const float*)d_in[0];
    const float* pool = (const float*)d_in[1];
    const float* lnw  = (const float*)d_in[2];
    const float* lnb  = (const float*)d_in[3];
    const float* W1   = (const float*)d_in[4];
    const float* b1   = (const float*)d_in[5];
    const float* W2   = (const float*)d_in[6];
    const float* b2   = (const float*)d_in[7];
    const float* qe   = (const float*)d_in[8];
    float* out = (float*)d_out;

    char* ws = (char*)d_ws;
    _Float16* xnh  = (_Float16*)ws;                                   // 2 MB
    _Float16* lnwh = (_Float16*)(ws + (2u << 20));                    // 256 KB
    _Float16* lnbh = (_Float16*)(ws + (2u << 20) + (256u << 10));     // 256 KB
    float*    hp   = (float*)(ws + (4u << 20));                       // 32 MB (2 k-halves)

    hipLaunchKernelGGL(k_prep,  dim3(320),      dim3(256), 0, stream,
                       ns, pool, lnw, lnb, xnh, lnwh, lnbh);
    hipLaunchKernelGGL(k_gemm1, dim3(8, 32, 2), dim3(256), 0, stream,
                       xnh, lnwh, lnbh, W1, hp);
    hipLaunchKernelGGL(k_gemm2, dim3(4, 4, 32), dim3(256), 0, stream,
                       hp, b1, W2, b2, qe, pool, out);
}

// Round 3
// 446.482 us; speedup vs baseline: 1.0112x; 1.0112x over previous
//
#include <hip/hip_runtime.h>
#include <hip/hip_fp16.h>

typedef _Float16 h8v __attribute__((ext_vector_type(8)));  // arithmetic type
typedef __fp16   hf8 __attribute__((ext_vector_type(8)));  // builtin ABI type
typedef float    f4v __attribute__((ext_vector_type(4)));
typedef unsigned int u32;

#define DEV __device__ __forceinline__

constexpr int NB  = 256;   // batch
constexpr int GG  = 4096;  // global_info_dim
constexpr int D1  = 512;   // 2H
constexpr int HD  = 256;   // H

// fp16 LDS tile, 32 dwords (64 halves) per row, XOR-swizzled at 16B granule
DEV int swz(int row, int c) {   // c = dword col in [0,32)
    return row*32 + ((((c>>2) ^ (row & 7)) & 7) << 2) + (c & 3);
}
DEV u32 pk2(float a, float b) {
    auto r = __builtin_amdgcn_cvt_pkrtz(a, b);   // __fp16 x2
    return __builtin_bit_cast(u32, r);
}
DEV u32 packh(_Float16 lo, _Float16 hi) {
    return (u32)__builtin_bit_cast(unsigned short, lo)
         | ((u32)__builtin_bit_cast(unsigned short, hi) << 16);
}
DEV f4v mfma16(h8v a, hf8 b, f4v c) {
    return __builtin_amdgcn_mfma_f32_16x16x32_f16(
        __builtin_bit_cast(hf8, a), b, c, 0, 0, 0);
}

// ---------- kernel 1: LN stats -> xn fp16; W2 -> fp16 ----------------------
__global__ __launch_bounds__(256) void k_prep(
        const float* __restrict__ ns, const float* __restrict__ pools,
        const float* __restrict__ W2,
        _Float16* __restrict__ xnh, _Float16* __restrict__ w2h)
{
    const int t = threadIdx.x;
    const int bid = blockIdx.x;
    if (bid < NB) {
        f4v v[4];
        float s = 0.f, s2 = 0.f;
        #pragma unroll
        for (int p = 0; p < 4; ++p) {
            int i4 = t + 256*p;
            const float* src = (i4 < 512) ? (ns + (size_t)bid*2048 + i4*4)
                                          : (pools + (size_t)bid*2048 + (i4-512)*4);
            v[p] = *(const f4v*)src;
            #pragma unroll
            for (int j = 0; j < 4; ++j) { s += v[p][j]; s2 += v[p][j]*v[p][j]; }
        }
        #pragma unroll
        for (int o = 32; o > 0; o >>= 1) { s += __shfl_down(s, o); s2 += __shfl_down(s2, o); }
        __shared__ float red[8];
        if ((t & 63) == 0) { red[t>>6] = s; red[4 + (t>>6)] = s2; }
        __syncthreads();
        float ts   = red[0]+red[1]+red[2]+red[3];
        float ts2  = red[4]+red[5]+red[6]+red[7];
        float mu   = ts  * (1.f/4096.f);
        float var  = ts2 * (1.f/4096.f) - mu*mu;
        float rstd = rsqrtf(var + 1e-5f);
        #pragma unroll
        for (int p = 0; p < 4; ++p) {
            int i4 = t + 256*p;
            u32 w0 = pk2((v[p][0]-mu)*rstd, (v[p][1]-mu)*rstd);
            u32 w1 = pk2((v[p][2]-mu)*rstd, (v[p][3]-mu)*rstd);
            *(uint2*)(xnh + (size_t)bid*GG + i4*4) = make_uint2(w0, w1);
        }
    } else {
        // 2048 blocks: cast W2 (32*512*256 f32) to fp16
        const size_t base = (size_t)(bid - NB)*2048 + t*8;
        f4v a0 = *(const f4v*)(W2 + base);
        f4v a1 = *(const f4v*)(W2 + base + 4);
        uint4 o; o.x = pk2(a0[0],a0[1]); o.y = pk2(a0[2],a0[3]);
                 o.z = pk2(a1[0],a1[1]); o.w = pk2(a1[2],a1[3]);
        *(uint4*)(w2h + base) = o;
    }
}

// ---------- kernel 2: hp = xn @ (lnw*W1), bias_p = lnb @ W1 -----------------
// grid (8 dt, 32 n, 2 ks); block 256 = 4 waves; BM=256 BN=64 BK=64.
// A (xn frags) direct from global (L2-hot, no VALU between load and MFMA);
// B = W1 scaled by lnw[g] in f32 during staging, packed fp16 into swizzled LDS.
// hp stored fragment-native: [ks][n][dt][w][mi][ni][r][lane] (256B/instr).
__global__ __launch_bounds__(256, 2) void k_gemm1(
        const _Float16* __restrict__ xnh, const float* __restrict__ lnw,
        const float* __restrict__ lnb, const float* __restrict__ W1,
        float* __restrict__ hp, float* __restrict__ bias_p)
{
    const int dt = blockIdx.x;
    const int n  = blockIdx.y;
    const int ks = blockIdx.z;
    const int t  = threadIdx.x;
    const int l  = t & 63;
    const int w  = t >> 6;

    __shared__ u32 lb[64*32];

    const float* W1p = W1  + ((size_t)n*GG + (size_t)ks*2048)*D1 + dt*64;
    const float* lwp = lnw + n*GG + ks*2048;
    const float* lbp = lnb + n*GG + ks*2048;
    const _Float16* xb = xnh + ks*2048;

    const int d0 = 4*(t & 15);
    const int g0 = 4*(t >> 4);
    int wp[4];
    #pragma unroll
    for (int i = 0; i < 4; ++i) wp[i] = swz(d0 + i, g0 >> 1);

    int rp[2][4];
    #pragma unroll
    for (int kc = 0; kc < 2; ++kc)
        #pragma unroll
        for (int ni = 0; ni < 4; ++ni) {
            int nr = ni*16 + (l & 15);
            rp[kc][ni] = nr*32 + ((((kc*4 + (l >> 4)) ^ (nr & 7)) & 7) << 2);
        }

    const int r0 = w*64;
    const _Float16* xrow[4];
    #pragma unroll
    for (int mi = 0; mi < 4; ++mi)
        xrow[mi] = xb + (size_t)(r0 + mi*16 + (l & 15))*GG + 8*(l >> 4);

    f4v st[4], lnwv, lnbv;
    #pragma unroll
    for (int p = 0; p < 4; ++p)
        st[p] = *(const f4v*)(W1p + (size_t)(g0 + p)*D1 + d0);
    lnwv = *(const f4v*)(lwp + g0);
    lnbv = *(const f4v*)(lbp + g0);

    f4v acc[4][4];
    #pragma unroll
    for (int mi = 0; mi < 4; ++mi)
        #pragma unroll
        for (int ni = 0; ni < 4; ++ni)
            #pragma unroll
            for (int r = 0; r < 4; ++r) acc[mi][ni][r] = 0.f;
    f4v bacc; bacc[0]=bacc[1]=bacc[2]=bacc[3]=0.f;

    for (int kt = 0; kt < 32; ++kt) {
        __syncthreads();
        // stage: bias partial (raw W1), scale by lnw, pack, swizzled write
        f4v sc[4];
        #pragma unroll
        for (int p = 0; p < 4; ++p) {
            bacc += lnbv[p] * st[p];
            sc[p] = st[p] * lnwv[p];
        }
        #pragma unroll
        for (int i = 0; i < 4; ++i) {
            u32 lo = pk2(sc[0][i], sc[1][i]);
            u32 hi = pk2(sc[2][i], sc[3][i]);
            *(uint2*)&lb[wp[i]] = make_uint2(lo, hi);
        }
        __syncthreads();
        // prefetch next W1/lnw/lnb tile into regs (consumed next staging)
        if (kt + 1 < 32) {
            const float* src = W1p + (size_t)(kt + 1)*64*D1;
            #pragma unroll
            for (int p = 0; p < 4; ++p)
                st[p] = *(const f4v*)(src + (size_t)(g0 + p)*D1 + d0);
            lnwv = *(const f4v*)(lwp + (kt+1)*64 + g0);
            lnbv = *(const f4v*)(lbp + (kt+1)*64 + g0);
        }
        // A fragments for THIS tile: 8 clean 16B loads, no dependent VALU
        h8v xa[2][4];
        #pragma unroll
        for (int kc = 0; kc < 2; ++kc)
            #pragma unroll
            for (int mi = 0; mi < 4; ++mi)
                xa[kc][mi] = *(const h8v*)(xrow[mi] + kt*64 + kc*32);
        #pragma unroll
        for (int kc = 0; kc < 2; ++kc)
            #pragma unroll
            for (int ni = 0; ni < 4; ++ni) {
                hf8 bf = __builtin_bit_cast(hf8, *(const uint4*)&lb[rp[kc][ni]]);
                #pragma unroll
                for (int mi = 0; mi < 4; ++mi)
                    acc[mi][ni] = mfma16(xa[kc][mi], bf, acc[mi][ni]);
            }
    }

    // reduce bias partials: 256 threads -> 64 columns
    __syncthreads();
    float* fl = (float*)lb;
    *(f4v*)(fl + 4*t) = bacc;
    __syncthreads();
    if (t < 64) {
        float s = 0.f;
        int c = t >> 2, i = t & 3;
        #pragma unroll
        for (int j = 0; j < 16; ++j) s += fl[(16*j + c)*4 + i];
        bias_p[(ks*32 + n)*D1 + dt*64 + t] = s;
    }

    float* outp = hp + ((size_t)(ks*32 + n)*8 + dt)*16384;
    #pragma unroll
    for (int mi = 0; mi < 4; ++mi)
        #pragma unroll
        for (int ni = 0; ni < 4; ++ni)
            #pragma unroll
            for (int r = 0; r < 4; ++r)
                outp[(((w*4 + mi)*4 + ni)*4 + r)*64 + l] = acc[mi][ni][r];
}

// ---------- kernel 3: out = silu(hp0+hp1+bias+b1) @ W2h + b2 + qe + pools ---
// grid (64, 8): x = n*2+ht, y = bt  (bt-siblings share blockIdx%8 -> same XCD
// -> W2h slice L2-served). BM=32, BN=128, 4 waves of 32x32.
__global__ __launch_bounds__(256, 2) void k_gemm2(
        const float* __restrict__ hp, const float* __restrict__ bias_p,
        const float* __restrict__ b1, const _Float16* __restrict__ w2h,
        const float* __restrict__ b2, const float* __restrict__ qe,
        const float* __restrict__ pools, float* __restrict__ out)
{
    const int n  = blockIdx.x >> 1;
    const int ht = blockIdx.x & 1;
    const int bt = blockIdx.y;
    const int t  = threadIdx.x;
    const int l  = t & 63;
    const int wc = t >> 6;

    __shared__ u32 la[32*32];
    __shared__ u32 lbs[128*32];

    // ---- A staging geometry (hp fragment-native inverse map) ----
    const int row32 = t >> 3, koff = (t & 7)*8;
    const int brow  = bt*32 + row32;
    const int Fo = (((brow>>6)*4 + ((brow>>4)&3))*4)*256 + (brow&3)*64 + ((brow>>2)&3)*16
                 + ((koff>>4))*256 + (koff & 15);
    const float* hp0 = hp + (size_t)n*8*16384 + Fo;            // + kt*16384
    const float* hp1 = hp0 + (size_t)32*8*16384;
    const float* bpp0 = bias_p + n*D1 + koff;                  // + kt*64
    const float* bpp1 = bpp0 + 32*D1;
    const float* b1p  = b1 + n*D1 + koff;
    const int wpa = row32*32 + (((t & 7) ^ (row32 & 7)) << 2); // b128-aligned

    // ---- B staging geometry ----
    const int g0 = 4*(t >> 4), d0 = 8*(t & 15);
    const _Float16* w2p = w2h + (size_t)n*D1*HD + ht*128 + d0; // + (kt*64+g0+p)*256

    int rpa[2][2], rpb[2][2];
    #pragma unroll
    for (int kc = 0; kc < 2; ++kc) {
        #pragma unroll
        for (int mi = 0; mi < 2; ++mi) {
            int row = mi*16 + (l & 15);
            rpa[kc][mi] = row*32 + ((((kc*4 + (l >> 4)) ^ (row & 7)) & 7) << 2);
        }
        #pragma unroll
        for (int ni = 0; ni < 2; ++ni) {
            int col = wc*32 + ni*16 + (l & 15);
            rpb[kc][ni] = col*32 + ((((kc*4 + (l >> 4)) ^ (col & 7)) & 7) << 2);
        }
    }

    f4v acc[2][2];
    #pragma unroll
    for (int mi = 0; mi < 2; ++mi)
        #pragma unroll
        for (int ni = 0; ni < 2; ++ni)
            #pragma unroll
            for (int r = 0; r < 4; ++r) acc[mi][ni][r] = 0.f;

    for (int kt = 0; kt < 8; ++kt) {
        // issue all staging loads up front
        f4v a00 = *(const f4v*)(hp0 + kt*16384);
        f4v a01 = *(const f4v*)(hp0 + kt*16384 + 4);
        f4v a10 = *(const f4v*)(hp1 + kt*16384);
        f4v a11 = *(const f4v*)(hp1 + kt*16384 + 4);
        f4v p0a = *(const f4v*)(bpp0 + kt*64), p0b = *(const f4v*)(bpp0 + kt*64 + 4);
        f4v p1a = *(const f4v*)(bpp1 + kt*64), p1b = *(const f4v*)(bpp1 + kt*64 + 4);
        f4v b1a = *(const f4v*)(b1p + kt*64),  b1b = *(const f4v*)(b1p + kt*64 + 4);
        h8v wv[4];
        #pragma unroll
        for (int p = 0; p < 4; ++p)
            wv[p] = *(const h8v*)(w2p + (size_t)(kt*64 + g0 + p)*HD);

        __syncthreads();   // previous tile's fragment reads done
        // A: sum partials + bias + b1, SiLU, pack fp16, swizzled b128 write
        f4v x0 = a00 + a10 + p0a + p1a + b1a;
        f4v x1 = a01 + a11 + p0b + p1b + b1b;
        float y[8];
        #pragma unroll
        for (int j = 0; j < 4; ++j) {
            y[j]   = __fdividef(x0[j], 1.f + __expf(-x0[j]));
            y[4+j] = __fdividef(x1[j], 1.f + __expf(-x1[j]));
        }
        uint4 pa;
        pa.x = pk2(y[0],y[1]); pa.y = pk2(y[2],y[3]);
        pa.z = pk2(y[4],y[5]); pa.w = pk2(y[6],y[7]);
        *(uint4*)&la[wpa] = pa;
        // B: per-thread 4x8 transpose, rotated col order to spread banks
        #pragma unroll
        for (int j0 = 0; j0 < 8; ++j0) {
            int j = (j0 + (t & 7)) & 7;
            int col = d0 + j;
            u32 lo = packh(wv[0][j], wv[1][j]);
            u32 hi = packh(wv[2][j], wv[3][j]);
            int off = col*32 + ((((t >> 5) ^ (col & 7)) & 7) << 2) + ((g0 >> 1) & 3);
            *(uint2*)&lbs[off] = make_uint2(lo, hi);
        }
        __syncthreads();
        #pragma unroll
        for (int kc = 0; kc < 2; ++kc) {
            h8v af[2]; hf8 bf[2];
            #pragma unroll
            for (int mi = 0; mi < 2; ++mi)
                af[mi] = __builtin_bit_cast(h8v, *(const uint4*)&la[rpa[kc][mi]]);
            #pragma unroll
            for (int ni = 0; ni < 2; ++ni)
                bf[ni] = __builtin_bit_cast(hf8, *(const uint4*)&lbs[rpb[kc][ni]]);
            #pragma unroll
            for (int mi = 0; mi < 2; ++mi)
                #pragma unroll
                for (int ni = 0; ni < 2; ++ni)
                    acc[mi][ni] = mfma16(af[mi], bf[ni], acc[mi][ni]);
        }
    }

    const int s = n >> 2;
    #pragma unroll
    for (int ni = 0; ni < 2; ++ni) {
        int hh = ht*128 + wc*32 + ni*16 + (l & 15);
        float add0 = b2[n*HD + hh] + qe[n*HD + hh];
        #pragma unroll
        for (int mi = 0; mi < 2; ++mi)
            #pragma unroll
            for (int r = 0; r < 4; ++r) {
                int br = bt*32 + mi*16 + (l >> 4)*4 + r;
                out[((size_t)br*32 + n)*HD + hh] =
                    acc[mi][ni][r] + add0 + pools[(size_t)br*2048 + s*HD + hh];
            }
    }
}

extern "C" void kernel_launch(void* const* d_in, const int* in_sizes, int n_in,
                              void* d_out, int out_size, void* d_ws, size_t ws_size,
                              hipStream_t stream) {
    const float* ns   = (const float*)d_in[0];
    const float* pool = (const float*)d_in[1];
    const float* lnw  = (const float*)d_in[2];
    const float* lnb  = (const float*)d_in[3];
    const float* W1   = (const float*)d_in[4];
    const float* b1   = (const float*)d_in[5];
    const float* W2   = (const float*)d_in[6];
    const float* b2   = (const float*)d_in[7];
    const float* qe   = (const float*)d_in[8];
    float* out = (float*)d_out;

    char* ws = (char*)d_ws;
    _Float16* xnh    = (_Float16*)ws;                      // 2 MB
    _Float16* w2h    = (_Float16*)(ws + (2u  << 20));      // 8 MB
    float*    bias_p = (float*)   (ws + (10u << 20));      // 128 KB
    float*    hp     = (float*)   (ws + (16u << 20));      // 32 MB

    hipLaunchKernelGGL(k_prep,  dim3(NB + 2048), dim3(256), 0, stream,
                       ns, pool, W2, xnh, w2h);
    hipLaunchKernelGGL(k_gemm1, dim3(8, 32, 2),  dim3(256), 0, stream,
                       xnh, lnw, lnb, W1, hp, bias_p);
    hipLaunchKernelGGL(k_gemm2, dim3(64, 8),     dim3(256), 0, stream,
                       hp, bias_p, b1, w2h, b2, qe, pool, out);
}